// Round 11
// baseline (287.038 us; speedup 1.0000x reference)
//
#include <hip/hip_runtime.h>
#include <hip/hip_bf16.h>

// Round 11: occupancy push on both hot kernels.
//  gemm1: 64x128 tile, reg-prefetch single-barrier K-loop (r10 gemm2_db structure),
//         1440 blocks = 5.6/CU (vs 2.8), launch_bounds(256,6). M-fastest grid.
//  attn:  split-K over key halves (partials additive since no-max softmax):
//         1536 blocks x 8 iters, fp32 partial O/l, + combine kernel. Qs dropped
//         from LDS (one-time global gather) -> 32.5 KB.
//  cvt3 / pack_all / gemm2 unchanged (gemm2 = same 64x128 kernel, fp32 out).
//
// ws layout (~79.5 MB; r3 proved >= 85.5 OK):
//   [A] qkv_b16: 3072*3840 bf16 (23.6 MB)  -- dead after pack; O0 (15.7 MB) aliases
//   [B] hs_b   : 3072*1280 bf16 (7.9 MB)   -- combine writes attn_b here
//   [C] qkvw_b : 3840*1280 bf16 (9.8 MB)   -- Qp aliases after gemm1
//   [D] projw_b: 1280*1280 bf16 (3.3 MB)
//   [E] Kp     : 9.4 MB   [F] Vp: 9.4 MB (96-wide, col80 = ones)
//   [G] O1     : 15.7 MB fp32   [H] l0,l1: 2 x 196 KB fp32

#define S_TOT 3072
#define DIM   1280
#define NH    16
#define HD    80
#define SEG   1024
#define TDIM  3840

typedef short v8s __attribute__((ext_vector_type(8)));
typedef float v4f __attribute__((ext_vector_type(4)));

__device__ __forceinline__ short f2bf(float v) {
  __hip_bfloat16 b = __float2bfloat16(v);
  return *reinterpret_cast<short*>(&b);
}

__device__ __forceinline__ float bf2f(short s) {
  unsigned u = ((unsigned)(unsigned short)s) << 16;
  float f;
  __builtin_memcpy(&f, &u, 4);
  return f;
}

// fused fp32->bf16 for hs / qkv_w / proj_w
#define CVT_N1 (S_TOT * DIM / 4)
#define CVT_N2 (TDIM * DIM / 4)
#define CVT_N3 (DIM * DIM / 4)
__global__ __launch_bounds__(256) void cvt3(const float* __restrict__ in1,
                                            const float* __restrict__ in2,
                                            const float* __restrict__ in3,
                                            __hip_bfloat16* __restrict__ o1,
                                            __hip_bfloat16* __restrict__ o2,
                                            __hip_bfloat16* __restrict__ o3) {
  int i = blockIdx.x * 256 + threadIdx.x;
  const float* in;
  __hip_bfloat16* out;
  if (i < CVT_N1) { in = in1; out = o1; }
  else if (i < CVT_N1 + CVT_N2) { in = in2; out = o2; i -= CVT_N1; }
  else { in = in3; out = o3; i -= CVT_N1 + CVT_N2; }
  const float4 v = ((const float4*)in)[i];
  __hip_bfloat162 p0, p1;
  p0.x = __float2bfloat16(v.x); p0.y = __float2bfloat16(v.y);
  p1.x = __float2bfloat16(v.z); p1.y = __float2bfloat16(v.w);
  __hip_bfloat162* o = (__hip_bfloat162*)(out + (size_t)i * 4);
  o[0] = p0; o[1] = p1;
}

// ---------------- 64x128 GEMM, BK=32, reg-prefetch, 1 barrier/slab -----------
// C[M,N] = A[M,K] @ B[N,K]^T + bias[N]. Grid (M/64 fastest, N/128).
// 6 blocks/CU (LDS 24 KB), launch_bounds(256,6).
template <bool OUT_BF16>
__global__ __launch_bounds__(256, 6) void gemm64t(const __hip_bfloat16* __restrict__ A,
                                                  const __hip_bfloat16* __restrict__ B,
                                                  const float* __restrict__ bias,
                                                  void* __restrict__ Cout,
                                                  int M, int N, int K) {
  __shared__ __align__(16) short Abuf[2][2048];  // 8 KB
  __shared__ __align__(16) short Bbuf[2][4096];  // 16 KB
  const int tid  = threadIdx.x;
  const int wave = tid >> 6;
  const int lane = tid & 63;
  const int quad = lane >> 4;
  const int l16  = lane & 15;
  const int bm = blockIdx.x * 64;    // M fastest: consecutive blocks share B tile
  const int bn = blockIdx.y * 128;
  const int wm = (wave & 1) * 32;
  const int wn = (wave >> 1) * 64;

  const __hip_bfloat16* Ag  = A + (size_t)(bm + (tid & 63)) * K + (tid >> 6) * 8;
  const __hip_bfloat16* Bg0 = B + (size_t)(bn + (tid & 127)) * K + (tid >> 7) * 8;
  const __hip_bfloat16* Bg1 = Bg0 + 16;

  v4f acc[2][4];
  const v4f vz = {0.f, 0.f, 0.f, 0.f};
  #pragma unroll
  for (int i = 0; i < 2; ++i)
    #pragma unroll
    for (int j = 0; j < 4; ++j) acc[i][j] = vz;

  const int nk = K >> 5;
  v8s a0 = *(const v8s*)Ag;
  v8s b0 = *(const v8s*)Bg0, b1 = *(const v8s*)Bg1;
  *(v8s*)&Abuf[0][tid * 8] = a0;
  *(v8s*)&Bbuf[0][tid * 8] = b0;  *(v8s*)&Bbuf[0][(tid + 256) * 8] = b1;
  __syncthreads();

  for (int k = 0; k < nk; ++k) {
    const int cur = k & 1;
    const bool more = (k + 1 < nk);
    v8s na0, nb0, nb1;
    if (more) {
      const int off = (k + 1) * 32;
      na0 = *(const v8s*)(Ag + off);
      nb0 = *(const v8s*)(Bg0 + off); nb1 = *(const v8s*)(Bg1 + off);
    }
    v8s af[2], bf[4];
    #pragma unroll
    for (int i = 0; i < 2; ++i)
      af[i] = *(const v8s*)&Abuf[cur][(quad * 64 + wm + i * 16 + l16) * 8];
    #pragma unroll
    for (int j = 0; j < 4; ++j)
      bf[j] = *(const v8s*)&Bbuf[cur][(quad * 128 + wn + j * 16 + l16) * 8];
    #pragma unroll
    for (int i = 0; i < 2; ++i)
      #pragma unroll
      for (int j = 0; j < 4; ++j)
        acc[i][j] = __builtin_amdgcn_mfma_f32_16x16x32_bf16(af[i], bf[j], acc[i][j], 0, 0, 0);
    if (more) {
      *(v8s*)&Abuf[1 - cur][tid * 8] = na0;
      *(v8s*)&Bbuf[1 - cur][tid * 8] = nb0;  *(v8s*)&Bbuf[1 - cur][(tid + 256) * 8] = nb1;
    }
    __syncthreads();
  }

  #pragma unroll
  for (int j = 0; j < 4; ++j) {
    const int col = bn + wn + j * 16 + l16;
    const float bj = bias[col];
    #pragma unroll
    for (int i = 0; i < 2; ++i) {
      const int row0 = bm + wm + i * 16 + quad * 4;
      #pragma unroll
      for (int r = 0; r < 4; ++r) {
        const float v = acc[i][j][r] + bj;
        if (OUT_BF16)
          ((__hip_bfloat16*)Cout)[(size_t)(row0 + r) * N + col] = __float2bfloat16(v);
        else
          ((float*)Cout)[(size_t)(row0 + r) * N + col] = v;
      }
    }
  }
}

// ---------------- merged pack kernel (unchanged) ----------------
#define QK_BLOCKS ((2 * S_TOT * 16 * 12) / 256)   // 4608
#define V_BLOCKS  ((3 * 16 * 16 * 8 * 96) / 256)  // 2304
__global__ __launch_bounds__(256) void pack_all(const __hip_bfloat16* __restrict__ qkv,
                                                const float* __restrict__ cos_,
                                                const float* __restrict__ sin_,
                                                short* __restrict__ Qp,
                                                short* __restrict__ Kp,
                                                short* __restrict__ Vp) {
  const int bid = blockIdx.x;
  if (bid < QK_BLOCKS) {
    const int idx = bid * 256 + threadIdx.x;
    const int kd = idx % 12;
    const int h  = (idx / 12) % 16;
    const int s  = (idx / 192) % S_TOT;
    const int p  = idx / (192 * S_TOT);
    const int seg = s >> 10, tb = (s >> 6) & 15, t = s & 63;
    short* out = (p ? Kp : Qp) +
                 ((size_t)(((seg * 16 + h) * 16 + tb) * 12 + kd) * 64 + t) * 8;
    short tmp[8];
    if (kd >= 10) {
      #pragma unroll
      for (int j = 0; j < 8; ++j) tmp[j] = 0;
      *(int4*)out = *(int4*)tmp;
      return;
    }
    const short* row = (const short*)qkv + (size_t)s * TDIM + p * DIM + h * HD;
    const int d0 = kd * 8;
    const v8s xm = *(const v8s*)(row + d0);
    const v8s xr = *(const v8s*)(row + d0 + ((kd < 5) ? 40 : -40));
    const float sgn = (kd < 5) ? -1.f : 1.f;
    const float scale = (p == 0) ? 0.111803398874989485f : 1.0f;
    #pragma unroll
    for (int j = 0; j < 8; ++j) {
      const int d = d0 + j;
      const float v = (bf2f(xm[j]) * cos_[s * HD + d] +
                       sgn * bf2f(xr[j]) * sin_[s * HD + d]) * scale;
      tmp[j] = f2bf(v);
    }
    *(int4*)out = *(int4*)tmp;
  } else {
    const int idx = (bid - QK_BLOCKS) * 256 + threadIdx.x;
    const int d  = idx % 96;
    const int td = (idx / 96) % 8;
    const int tb = (idx / 768) % 16;
    const int h  = (idx / (768 * 16)) % 16;
    const int seg = idx / (768 * 256);
    const int s0 = seg * SEG + tb * 64 + td * 8;
    const short* q = (const short*)qkv;
    short tmp[8];
    if (d < 80) {
      #pragma unroll
      for (int j = 0; j < 8; ++j)
        tmp[j] = q[(size_t)(s0 + j) * TDIM + 2 * DIM + h * HD + d];
    } else {
      const short fill = (d == 80) ? (short)0x3F80 : (short)0;
      #pragma unroll
      for (int j = 0; j < 8; ++j) tmp[j] = fill;
    }
    *(int4*)(Vp + (size_t)idx * 8) = *(int4*)tmp;
  }
}

// ---------------- flash MFMA attention, split-K (key halves) ----------------
// grid (16 qtiles, NH*2 (h, half), 3 segs); each block does 8 key-blocks and
// writes fp32 partial O (unnormalized) + partial l. Partials are additive
// because softmax has no max subtraction. Q frags gathered from global (no Qs).
__global__ __launch_bounds__(256, 3) void attn_mfma(const short* __restrict__ Qp,
                                                    const short* __restrict__ Kp,
                                                    const short* __restrict__ Vp,
                                                    float* __restrict__ O0,
                                                    float* __restrict__ O1,
                                                    float* __restrict__ l0,
                                                    float* __restrict__ l1) {
  __shared__ __align__(16) short Ks[64 * 96];     // 12 KB
  __shared__ __align__(16) short Vs[64 * 96];     // 12 KB
  __shared__ __align__(16) short Ps[4][16 * 68];  // 8.5 KB, wave-private

  const int qt   = blockIdx.x;
  const int h    = blockIdx.y & 15;
  const int half = blockIdx.y >> 4;
  const int seg  = blockIdx.z;
  const int tid  = threadIdx.x;
  const int wave = tid >> 6;
  const int lane = tid & 63;
  const int quad = lane >> 4;
  const int l16  = lane & 15;
  const int sh16 = seg * 16 + h;

  float* Opart = half ? O1 : O0;
  float* lpart = half ? l1 : l0;

  const short* Qg = Qp + (size_t)(sh16 * 16 + qt) * 6144;
  const short* Kg = Kp + (size_t)(sh16 * 16 + half * 8) * 6144;
  const short* Vg = Vp + (size_t)(sh16 * 16 + half * 8) * 6144;

  // Q A-frags straight from global (slab layout == LDS image)
  v8s af[3];
  #pragma unroll
  for (int ks = 0; ks < 3; ++ks)
    af[ks] = *(const v8s*)(Qg + ((ks * 4 + quad) * 64 + wave * 16 + l16) * 8);

  // prologue: K/V(0) -> regs -> LDS
  v8s kr[3], vr[3];
  #pragma unroll
  for (int it = 0; it < 3; ++it) {
    const int o = (it * 256 + tid) * 8;
    kr[it] = *(const v8s*)(Kg + o);
    vr[it] = *(const v8s*)(Vg + o);
  }
  #pragma unroll
  for (int it = 0; it < 3; ++it) {
    const int o = (it * 256 + tid) * 8;
    *(v8s*)&Ks[o] = kr[it];
    *(v8s*)&Vs[o] = vr[it];
  }
  __syncthreads();

  v4f o4[6];  // n=0..4: O tiles; n=5: ones-column -> row sums l
  const v4f vz = {0.f, 0.f, 0.f, 0.f};
  #pragma unroll
  for (int n = 0; n < 6; ++n) o4[n] = vz;

  for (int kb = 0; kb < 8; ++kb) {
    const bool more = (kb + 1 < 8);
    if (more) {
      const size_t base = (size_t)(kb + 1) * 6144;
      #pragma unroll
      for (int it = 0; it < 3; ++it) {
        const int o = (it * 256 + tid) * 8;
        kr[it] = *(const v8s*)(Kg + base + o);
        vr[it] = *(const v8s*)(Vg + base + o);
      }
    }

    v4f s4[4];
    #pragma unroll
    for (int j = 0; j < 4; ++j) {
      s4[j] = vz;
      #pragma unroll
      for (int ks = 0; ks < 3; ++ks) {
        const v8s bf = *(const v8s*)&Ks[((ks * 4 + quad) * 64 + j * 16 + l16) * 8];
        s4[j] = __builtin_amdgcn_mfma_f32_16x16x32_bf16(af[ks], bf, s4[j], 0, 0, 0);
      }
    }

    #pragma unroll
    for (int reg = 0; reg < 4; ++reg)
      #pragma unroll
      for (int j = 0; j < 4; ++j)
        Ps[wave][(quad * 4 + reg) * 68 + j * 16 + l16] = f2bf(__expf(s4[j][reg]));

    v8s pa[2];
    #pragma unroll
    for (int kp = 0; kp < 2; ++kp)
      pa[kp] = *(const v8s*)&Ps[wave][l16 * 68 + kp * 32 + quad * 8];
    #pragma unroll
    for (int n = 0; n < 6; ++n) {
      #pragma unroll
      for (int kp = 0; kp < 2; ++kp) {
        const v8s vb = *(const v8s*)&Vs[((kp * 4 + quad) * 96 + n * 16 + l16) * 8];
        o4[n] = __builtin_amdgcn_mfma_f32_16x16x32_bf16(pa[kp], vb, o4[n], 0, 0, 0);
      }
    }

    __syncthreads();
    if (more) {
      #pragma unroll
      for (int it = 0; it < 3; ++it) {
        const int o = (it * 256 + tid) * 8;
        *(v8s*)&Ks[o] = kr[it];
        *(v8s*)&Vs[o] = vr[it];
      }
    }
    __syncthreads();
  }

  // write fp32 partials (unnormalized) + partial row sums
  const int row0 = seg * SEG + qt * 64 + wave * 16 + quad * 4;
  #pragma unroll
  for (int n = 0; n < 5; ++n) {
    const int col = h * HD + n * 16 + l16;
    #pragma unroll
    for (int r = 0; r < 4; ++r)
      Opart[(size_t)(row0 + r) * DIM + col] = o4[n][r];
  }
  if (l16 == 0) {
    #pragma unroll
    for (int r = 0; r < 4; ++r)
      lpart[(size_t)(row0 + r) * NH + h] = o4[5][r];
  }
}

// combine: attn_b = bf16((O0+O1) / (l0+l1))
__global__ __launch_bounds__(256) void attn_combine(const float* __restrict__ O0,
                                                    const float* __restrict__ O1,
                                                    const float* __restrict__ l0,
                                                    const float* __restrict__ l1,
                                                    __hip_bfloat16* __restrict__ out) {
  const int i = blockIdx.x * 256 + threadIdx.x;  // S_TOT*DIM/4 threads
  const int row = i / (DIM / 4);
  const int c4  = (i % (DIM / 4)) * 4;
  const int h   = c4 / HD;
  const float inv = 1.f / (l0[row * NH + h] + l1[row * NH + h]);
  const float4 a = *(const float4*)&O0[(size_t)row * DIM + c4];
  const float4 b = *(const float4*)&O1[(size_t)row * DIM + c4];
  __hip_bfloat162 p0, p1;
  p0.x = __float2bfloat16((a.x + b.x) * inv);
  p0.y = __float2bfloat16((a.y + b.y) * inv);
  p1.x = __float2bfloat16((a.z + b.z) * inv);
  p1.y = __float2bfloat16((a.w + b.w) * inv);
  *(__hip_bfloat162*)&out[(size_t)row * DIM + c4]     = p0;
  *(__hip_bfloat162*)&out[(size_t)row * DIM + c4 + 2] = p1;
}

extern "C" void kernel_launch(void* const* d_in, const int* in_sizes, int n_in,
                              void* d_out, int out_size, void* d_ws, size_t ws_size,
                              hipStream_t stream) {
  (void)in_sizes; (void)n_in; (void)out_size; (void)ws_size;
  const float* hs     = (const float*)d_in[0];
  const float* cosp   = (const float*)d_in[1];
  const float* sinp   = (const float*)d_in[2];
  const float* qkv_w  = (const float*)d_in[3];
  const float* qkv_b  = (const float*)d_in[4];
  const float* proj_w = (const float*)d_in[5];
  const float* proj_b = (const float*)d_in[6];

  float* out_f = (float*)d_out;
  __hip_bfloat16* qkv_b16 = (__hip_bfloat16*)d_ws;                     // [A]
  __hip_bfloat16* hs_b    = qkv_b16 + (size_t)S_TOT * TDIM;            // [B]
  __hip_bfloat16* qkvw_b  = hs_b + (size_t)S_TOT * DIM;                // [C]
  __hip_bfloat16* projw_b = qkvw_b + (size_t)TDIM * DIM;               // [D]
  short* Qp = (short*)qkvw_b;                                          // alias [C]
  short* Kp = (short*)(projw_b + (size_t)DIM * DIM);                   // [E]
  short* Vp = Kp + (size_t)3 * 16 * 16 * 6144;                         // [F]
  float* O1 = (float*)(Vp + (size_t)3 * 16 * 16 * 6144);               // [G]
  float* l0 = O1 + (size_t)S_TOT * DIM;                                // [H]
  float* l1 = l0 + (size_t)S_TOT * NH;
  float* O0 = (float*)d_ws;                                            // alias [A]
  __hip_bfloat16* attn_b = hs_b;                                       // alias [B]

  cvt3<<<(CVT_N1 + CVT_N2 + CVT_N3) / 256, 256, 0, stream>>>(
      hs, qkv_w, proj_w, hs_b, qkvw_b, projw_b);

  gemm64t<true><<<dim3(S_TOT / 64, TDIM / 128), 256, 0, stream>>>(
      hs_b, qkvw_b, qkv_b, (void*)qkv_b16, S_TOT, TDIM, DIM);

  pack_all<<<QK_BLOCKS + V_BLOCKS, 256, 0, stream>>>(qkv_b16, cosp, sinp, Qp, Kp, Vp);

  attn_mfma<<<dim3(16, NH * 2, 3), 256, 0, stream>>>(Qp, Kp, Vp, O0, O1, l0, l1);
  attn_combine<<<(S_TOT * DIM / 4) / 256, 256, 0, stream>>>(O0, O1, l0, l1, attn_b);

  gemm64t<false><<<dim3(S_TOT / 64, DIM / 128), 256, 0, stream>>>(
      attn_b, projw_b, proj_b, (void*)out_f, S_TOT, DIM, DIM);
}

// Round 12
// 262.151 us; speedup vs baseline: 1.0949x; 1.0949x over previous
//
#include <hip/hip_runtime.h>
#include <hip/hip_bf16.h>

// Round 12: best-known pieces recombined.
//  gemm1: r10 gemm128_db EXACT (77 us measured best; M-fastest grid).
//  gemm2: r10 gemm2_db EXACT (64x128, no launch_bounds cap).
//  attn:  r11 split-K over key halves + combine (r11 totals imply ~15-20 us win;
//         r11's gemm regression was launch_bounds(256,6) VGPR-remat, now avoided).
//
// ws layout (~79.5 MB):
//   [A] qkv_b16: 3072*3840 bf16 (23.6 MB)  -- dead after pack; O0 (15.7 MB) aliases
//   [B] hs_b   : 3072*1280 bf16 (7.9 MB)   -- combine writes attn_b here
//   [C] qkvw_b : 3840*1280 bf16 (9.8 MB)   -- Qp aliases after gemm1
//   [D] projw_b: 1280*1280 bf16 (3.3 MB)
//   [E] Kp     : 9.4 MB   [F] Vp: 9.4 MB (96-wide, col80 = ones)
//   [G] O1     : 15.7 MB fp32   [H] l0,l1: 2 x 196 KB fp32

#define S_TOT 3072
#define DIM   1280
#define NH    16
#define HD    80
#define SEG   1024
#define TDIM  3840

typedef short v8s __attribute__((ext_vector_type(8)));
typedef float v4f __attribute__((ext_vector_type(4)));

__device__ __forceinline__ short f2bf(float v) {
  __hip_bfloat16 b = __float2bfloat16(v);
  return *reinterpret_cast<short*>(&b);
}

__device__ __forceinline__ float bf2f(short s) {
  unsigned u = ((unsigned)(unsigned short)s) << 16;
  float f;
  __builtin_memcpy(&f, &u, 4);
  return f;
}

#define CVT_N1 (S_TOT * DIM / 4)
#define CVT_N2 (TDIM * DIM / 4)
#define CVT_N3 (DIM * DIM / 4)
__global__ __launch_bounds__(256) void cvt3(const float* __restrict__ in1,
                                            const float* __restrict__ in2,
                                            const float* __restrict__ in3,
                                            __hip_bfloat16* __restrict__ o1,
                                            __hip_bfloat16* __restrict__ o2,
                                            __hip_bfloat16* __restrict__ o3) {
  int i = blockIdx.x * 256 + threadIdx.x;
  const float* in;
  __hip_bfloat16* out;
  if (i < CVT_N1) { in = in1; out = o1; }
  else if (i < CVT_N1 + CVT_N2) { in = in2; out = o2; i -= CVT_N1; }
  else { in = in3; out = o3; i -= CVT_N1 + CVT_N2; }
  const float4 v = ((const float4*)in)[i];
  __hip_bfloat162 p0, p1;
  p0.x = __float2bfloat16(v.x); p0.y = __float2bfloat16(v.y);
  p1.x = __float2bfloat16(v.z); p1.y = __float2bfloat16(v.w);
  __hip_bfloat162* o = (__hip_bfloat162*)(out + (size_t)i * 4);
  o[0] = p0; o[1] = p1;
}

// ---------------- gemm1: 128x128, BK=32, reg-prefetch, M-fastest grid (r10) ----
__global__ __launch_bounds__(256) void gemm128_db(const __hip_bfloat16* __restrict__ A,
                                                  const __hip_bfloat16* __restrict__ B,
                                                  const float* __restrict__ bias,
                                                  __hip_bfloat16* __restrict__ C,
                                                  int M, int N, int K) {
  __shared__ __align__(16) short Abuf[2][4096];
  __shared__ __align__(16) short Bbuf[2][4096];
  const int tid  = threadIdx.x;
  const int wave = tid >> 6;
  const int lane = tid & 63;
  const int bm = blockIdx.x * 128;   // M fastest
  const int bn = blockIdx.y * 128;
  const int wm = (wave >> 1) * 64;
  const int wn = (wave & 1) * 64;

  const int r0 = tid & 127, kh0 = tid >> 7;
  const __hip_bfloat16* Ag0 = A + (size_t)(bm + r0) * K + kh0 * 8;
  const __hip_bfloat16* Ag1 = Ag0 + 16;
  const __hip_bfloat16* Bg0 = B + (size_t)(bn + r0) * K + kh0 * 8;
  const __hip_bfloat16* Bg1 = Bg0 + 16;

  v4f acc[4][4];
  const v4f vz = {0.f, 0.f, 0.f, 0.f};
  #pragma unroll
  for (int i = 0; i < 4; ++i)
    #pragma unroll
    for (int j = 0; j < 4; ++j) acc[i][j] = vz;

  const int kh = lane >> 4;
  const int lr = lane & 15;
  const int nk = K >> 5;

  v8s a0 = *(const v8s*)Ag0, a1 = *(const v8s*)Ag1;
  v8s b0 = *(const v8s*)Bg0, b1 = *(const v8s*)Bg1;
  *(v8s*)&Abuf[0][tid * 8] = a0;  *(v8s*)&Abuf[0][(tid + 256) * 8] = a1;
  *(v8s*)&Bbuf[0][tid * 8] = b0;  *(v8s*)&Bbuf[0][(tid + 256) * 8] = b1;
  __syncthreads();

  for (int k = 0; k < nk; ++k) {
    const int cur = k & 1;
    const bool more = (k + 1 < nk);
    v8s na0, na1, nb0, nb1;
    if (more) {
      const int off = (k + 1) * 32;
      na0 = *(const v8s*)(Ag0 + off); na1 = *(const v8s*)(Ag1 + off);
      nb0 = *(const v8s*)(Bg0 + off); nb1 = *(const v8s*)(Bg1 + off);
    }
    v8s af[4], bf[4];
    #pragma unroll
    for (int i = 0; i < 4; ++i) {
      af[i] = *(const v8s*)&Abuf[cur][(kh * 128 + wm + i * 16 + lr) * 8];
      bf[i] = *(const v8s*)&Bbuf[cur][(kh * 128 + wn + i * 16 + lr) * 8];
    }
    #pragma unroll
    for (int i = 0; i < 4; ++i)
      #pragma unroll
      for (int j = 0; j < 4; ++j)
        acc[i][j] = __builtin_amdgcn_mfma_f32_16x16x32_bf16(af[i], bf[j], acc[i][j], 0, 0, 0);
    if (more) {
      *(v8s*)&Abuf[1 - cur][tid * 8] = na0;  *(v8s*)&Abuf[1 - cur][(tid + 256) * 8] = na1;
      *(v8s*)&Bbuf[1 - cur][tid * 8] = nb0;  *(v8s*)&Bbuf[1 - cur][(tid + 256) * 8] = nb1;
    }
    __syncthreads();
  }

  const int lq = lane >> 4;
  #pragma unroll
  for (int j = 0; j < 4; ++j) {
    const int col = bn + wn + j * 16 + lr;
    const float bj = bias[col];
    #pragma unroll
    for (int i = 0; i < 4; ++i) {
      const int row0 = bm + wm + i * 16 + lq * 4;
      #pragma unroll
      for (int r = 0; r < 4; ++r)
        C[(size_t)(row0 + r) * N + col] = __float2bfloat16(acc[i][j][r] + bj);
    }
  }
}

// ---------------- gemm2: 64x128, BK=32, reg-prefetch, M-fastest grid (r10) -----
__global__ __launch_bounds__(256) void gemm2_db(const __hip_bfloat16* __restrict__ A,
                                                const __hip_bfloat16* __restrict__ B,
                                                const float* __restrict__ bias,
                                                float* __restrict__ C,
                                                int M, int N, int K) {
  __shared__ __align__(16) short Abuf[2][2048];
  __shared__ __align__(16) short Bbuf[2][4096];
  const int tid  = threadIdx.x;
  const int wave = tid >> 6;
  const int lane = tid & 63;
  const int quad = lane >> 4;
  const int l16  = lane & 15;
  const int bm = blockIdx.x * 64;    // M fastest
  const int bn = blockIdx.y * 128;
  const int wm = (wave & 1) * 32;
  const int wn = (wave >> 1) * 64;

  const __hip_bfloat16* Ag  = A + (size_t)(bm + (tid & 63)) * K + (tid >> 6) * 8;
  const __hip_bfloat16* Bg0 = B + (size_t)(bn + (tid & 127)) * K + (tid >> 7) * 8;
  const __hip_bfloat16* Bg1 = Bg0 + 16;

  v4f acc[2][4];
  const v4f vz = {0.f, 0.f, 0.f, 0.f};
  #pragma unroll
  for (int i = 0; i < 2; ++i)
    #pragma unroll
    for (int j = 0; j < 4; ++j) acc[i][j] = vz;

  const int nk = K >> 5;
  v8s a0 = *(const v8s*)Ag;
  v8s b0 = *(const v8s*)Bg0, b1 = *(const v8s*)Bg1;
  *(v8s*)&Abuf[0][tid * 8] = a0;
  *(v8s*)&Bbuf[0][tid * 8] = b0;  *(v8s*)&Bbuf[0][(tid + 256) * 8] = b1;
  __syncthreads();

  for (int k = 0; k < nk; ++k) {
    const int cur = k & 1;
    const bool more = (k + 1 < nk);
    v8s na0, nb0, nb1;
    if (more) {
      const int off = (k + 1) * 32;
      na0 = *(const v8s*)(Ag + off);
      nb0 = *(const v8s*)(Bg0 + off); nb1 = *(const v8s*)(Bg1 + off);
    }
    v8s af[2], bf[4];
    #pragma unroll
    for (int i = 0; i < 2; ++i)
      af[i] = *(const v8s*)&Abuf[cur][(quad * 64 + wm + i * 16 + l16) * 8];
    #pragma unroll
    for (int j = 0; j < 4; ++j)
      bf[j] = *(const v8s*)&Bbuf[cur][(quad * 128 + wn + j * 16 + l16) * 8];
    #pragma unroll
    for (int i = 0; i < 2; ++i)
      #pragma unroll
      for (int j = 0; j < 4; ++j)
        acc[i][j] = __builtin_amdgcn_mfma_f32_16x16x32_bf16(af[i], bf[j], acc[i][j], 0, 0, 0);
    if (more) {
      *(v8s*)&Abuf[1 - cur][tid * 8] = na0;
      *(v8s*)&Bbuf[1 - cur][tid * 8] = nb0;  *(v8s*)&Bbuf[1 - cur][(tid + 256) * 8] = nb1;
    }
    __syncthreads();
  }

  #pragma unroll
  for (int j = 0; j < 4; ++j) {
    const int col = bn + wn + j * 16 + l16;
    const float bj = bias[col];
    #pragma unroll
    for (int i = 0; i < 2; ++i) {
      const int row0 = bm + wm + i * 16 + quad * 4;
      #pragma unroll
      for (int r = 0; r < 4; ++r)
        C[(size_t)(row0 + r) * N + col] = acc[i][j][r] + bj;
    }
  }
}

// ---------------- merged pack kernel (unchanged) ----------------
#define QK_BLOCKS ((2 * S_TOT * 16 * 12) / 256)   // 4608
#define V_BLOCKS  ((3 * 16 * 16 * 8 * 96) / 256)  // 2304
__global__ __launch_bounds__(256) void pack_all(const __hip_bfloat16* __restrict__ qkv,
                                                const float* __restrict__ cos_,
                                                const float* __restrict__ sin_,
                                                short* __restrict__ Qp,
                                                short* __restrict__ Kp,
                                                short* __restrict__ Vp) {
  const int bid = blockIdx.x;
  if (bid < QK_BLOCKS) {
    const int idx = bid * 256 + threadIdx.x;
    const int kd = idx % 12;
    const int h  = (idx / 12) % 16;
    const int s  = (idx / 192) % S_TOT;
    const int p  = idx / (192 * S_TOT);
    const int seg = s >> 10, tb = (s >> 6) & 15, t = s & 63;
    short* out = (p ? Kp : Qp) +
                 ((size_t)(((seg * 16 + h) * 16 + tb) * 12 + kd) * 64 + t) * 8;
    short tmp[8];
    if (kd >= 10) {
      #pragma unroll
      for (int j = 0; j < 8; ++j) tmp[j] = 0;
      *(int4*)out = *(int4*)tmp;
      return;
    }
    const short* row = (const short*)qkv + (size_t)s * TDIM + p * DIM + h * HD;
    const int d0 = kd * 8;
    const v8s xm = *(const v8s*)(row + d0);
    const v8s xr = *(const v8s*)(row + d0 + ((kd < 5) ? 40 : -40));
    const float sgn = (kd < 5) ? -1.f : 1.f;
    const float scale = (p == 0) ? 0.111803398874989485f : 1.0f;
    #pragma unroll
    for (int j = 0; j < 8; ++j) {
      const int d = d0 + j;
      const float v = (bf2f(xm[j]) * cos_[s * HD + d] +
                       sgn * bf2f(xr[j]) * sin_[s * HD + d]) * scale;
      tmp[j] = f2bf(v);
    }
    *(int4*)out = *(int4*)tmp;
  } else {
    const int idx = (bid - QK_BLOCKS) * 256 + threadIdx.x;
    const int d  = idx % 96;
    const int td = (idx / 96) % 8;
    const int tb = (idx / 768) % 16;
    const int h  = (idx / (768 * 16)) % 16;
    const int seg = idx / (768 * 256);
    const int s0 = seg * SEG + tb * 64 + td * 8;
    const short* q = (const short*)qkv;
    short tmp[8];
    if (d < 80) {
      #pragma unroll
      for (int j = 0; j < 8; ++j)
        tmp[j] = q[(size_t)(s0 + j) * TDIM + 2 * DIM + h * HD + d];
    } else {
      const short fill = (d == 80) ? (short)0x3F80 : (short)0;
      #pragma unroll
      for (int j = 0; j < 8; ++j) tmp[j] = fill;
    }
    *(int4*)(Vp + (size_t)idx * 8) = *(int4*)tmp;
  }
}

// ---------------- flash MFMA attention, split-K over key halves (r11) ----------
__global__ __launch_bounds__(256, 3) void attn_mfma(const short* __restrict__ Qp,
                                                    const short* __restrict__ Kp,
                                                    const short* __restrict__ Vp,
                                                    float* __restrict__ O0,
                                                    float* __restrict__ O1,
                                                    float* __restrict__ l0,
                                                    float* __restrict__ l1) {
  __shared__ __align__(16) short Ks[64 * 96];
  __shared__ __align__(16) short Vs[64 * 96];
  __shared__ __align__(16) short Ps[4][16 * 68];

  const int qt   = blockIdx.x;
  const int h    = blockIdx.y & 15;
  const int half = blockIdx.y >> 4;
  const int seg  = blockIdx.z;
  const int tid  = threadIdx.x;
  const int wave = tid >> 6;
  const int lane = tid & 63;
  const int quad = lane >> 4;
  const int l16  = lane & 15;
  const int sh16 = seg * 16 + h;

  float* Opart = half ? O1 : O0;
  float* lpart = half ? l1 : l0;

  const short* Qg = Qp + (size_t)(sh16 * 16 + qt) * 6144;
  const short* Kg = Kp + (size_t)(sh16 * 16 + half * 8) * 6144;
  const short* Vg = Vp + (size_t)(sh16 * 16 + half * 8) * 6144;

  v8s af[3];
  #pragma unroll
  for (int ks = 0; ks < 3; ++ks)
    af[ks] = *(const v8s*)(Qg + ((ks * 4 + quad) * 64 + wave * 16 + l16) * 8);

  v8s kr[3], vr[3];
  #pragma unroll
  for (int it = 0; it < 3; ++it) {
    const int o = (it * 256 + tid) * 8;
    kr[it] = *(const v8s*)(Kg + o);
    vr[it] = *(const v8s*)(Vg + o);
  }
  #pragma unroll
  for (int it = 0; it < 3; ++it) {
    const int o = (it * 256 + tid) * 8;
    *(v8s*)&Ks[o] = kr[it];
    *(v8s*)&Vs[o] = vr[it];
  }
  __syncthreads();

  v4f o4[6];
  const v4f vz = {0.f, 0.f, 0.f, 0.f};
  #pragma unroll
  for (int n = 0; n < 6; ++n) o4[n] = vz;

  for (int kb = 0; kb < 8; ++kb) {
    const bool more = (kb + 1 < 8);
    if (more) {
      const size_t base = (size_t)(kb + 1) * 6144;
      #pragma unroll
      for (int it = 0; it < 3; ++it) {
        const int o = (it * 256 + tid) * 8;
        kr[it] = *(const v8s*)(Kg + base + o);
        vr[it] = *(const v8s*)(Vg + base + o);
      }
    }

    v4f s4[4];
    #pragma unroll
    for (int j = 0; j < 4; ++j) {
      s4[j] = vz;
      #pragma unroll
      for (int ks = 0; ks < 3; ++ks) {
        const v8s bf = *(const v8s*)&Ks[((ks * 4 + quad) * 64 + j * 16 + l16) * 8];
        s4[j] = __builtin_amdgcn_mfma_f32_16x16x32_bf16(af[ks], bf, s4[j], 0, 0, 0);
      }
    }

    #pragma unroll
    for (int reg = 0; reg < 4; ++reg)
      #pragma unroll
      for (int j = 0; j < 4; ++j)
        Ps[wave][(quad * 4 + reg) * 68 + j * 16 + l16] = f2bf(__expf(s4[j][reg]));

    v8s pa[2];
    #pragma unroll
    for (int kp = 0; kp < 2; ++kp)
      pa[kp] = *(const v8s*)&Ps[wave][l16 * 68 + kp * 32 + quad * 8];
    #pragma unroll
    for (int n = 0; n < 6; ++n) {
      #pragma unroll
      for (int kp = 0; kp < 2; ++kp) {
        const v8s vb = *(const v8s*)&Vs[((kp * 4 + quad) * 96 + n * 16 + l16) * 8];
        o4[n] = __builtin_amdgcn_mfma_f32_16x16x32_bf16(pa[kp], vb, o4[n], 0, 0, 0);
      }
    }

    __syncthreads();
    if (more) {
      #pragma unroll
      for (int it = 0; it < 3; ++it) {
        const int o = (it * 256 + tid) * 8;
        *(v8s*)&Ks[o] = kr[it];
        *(v8s*)&Vs[o] = vr[it];
      }
    }
    __syncthreads();
  }

  const int row0 = seg * SEG + qt * 64 + wave * 16 + quad * 4;
  #pragma unroll
  for (int n = 0; n < 5; ++n) {
    const int col = h * HD + n * 16 + l16;
    #pragma unroll
    for (int r = 0; r < 4; ++r)
      Opart[(size_t)(row0 + r) * DIM + col] = o4[n][r];
  }
  if (l16 == 0) {
    #pragma unroll
    for (int r = 0; r < 4; ++r)
      lpart[(size_t)(row0 + r) * NH + h] = o4[5][r];
  }
}

// combine: attn_b = bf16((O0+O1) / (l0+l1))
__global__ __launch_bounds__(256) void attn_combine(const float* __restrict__ O0,
                                                    const float* __restrict__ O1,
                                                    const float* __restrict__ l0,
                                                    const float* __restrict__ l1,
                                                    __hip_bfloat16* __restrict__ out) {
  const int i = blockIdx.x * 256 + threadIdx.x;
  const int row = i / (DIM / 4);
  const int c4  = (i % (DIM / 4)) * 4;
  const int h   = c4 / HD;
  const float inv = 1.f / (l0[row * NH + h] + l1[row * NH + h]);
  const float4 a = *(const float4*)&O0[(size_t)row * DIM + c4];
  const float4 b = *(const float4*)&O1[(size_t)row * DIM + c4];
  __hip_bfloat162 p0, p1;
  p0.x = __float2bfloat16((a.x + b.x) * inv);
  p0.y = __float2bfloat16((a.y + b.y) * inv);
  p1.x = __float2bfloat16((a.z + b.z) * inv);
  p1.y = __float2bfloat16((a.w + b.w) * inv);
  *(__hip_bfloat162*)&out[(size_t)row * DIM + c4]     = p0;
  *(__hip_bfloat162*)&out[(size_t)row * DIM + c4 + 2] = p1;
}

extern "C" void kernel_launch(void* const* d_in, const int* in_sizes, int n_in,
                              void* d_out, int out_size, void* d_ws, size_t ws_size,
                              hipStream_t stream) {
  (void)in_sizes; (void)n_in; (void)out_size; (void)ws_size;
  const float* hs     = (const float*)d_in[0];
  const float* cosp   = (const float*)d_in[1];
  const float* sinp   = (const float*)d_in[2];
  const float* qkv_w  = (const float*)d_in[3];
  const float* qkv_b  = (const float*)d_in[4];
  const float* proj_w = (const float*)d_in[5];
  const float* proj_b = (const float*)d_in[6];

  float* out_f = (float*)d_out;
  __hip_bfloat16* qkv_b16 = (__hip_bfloat16*)d_ws;                     // [A]
  __hip_bfloat16* hs_b    = qkv_b16 + (size_t)S_TOT * TDIM;            // [B]
  __hip_bfloat16* qkvw_b  = hs_b + (size_t)S_TOT * DIM;                // [C]
  __hip_bfloat16* projw_b = qkvw_b + (size_t)TDIM * DIM;               // [D]
  short* Qp = (short*)qkvw_b;                                          // alias [C]
  short* Kp = (short*)(projw_b + (size_t)DIM * DIM);                   // [E]
  short* Vp = Kp + (size_t)3 * 16 * 16 * 6144;                         // [F]
  float* O1 = (float*)(Vp + (size_t)3 * 16 * 16 * 6144);               // [G]
  float* l0 = O1 + (size_t)S_TOT * DIM;                                // [H]
  float* l1 = l0 + (size_t)S_TOT * NH;
  float* O0 = (float*)d_ws;                                            // alias [A]
  __hip_bfloat16* attn_b = hs_b;                                       // alias [B]

  cvt3<<<(CVT_N1 + CVT_N2 + CVT_N3) / 256, 256, 0, stream>>>(
      hs, qkv_w, proj_w, hs_b, qkvw_b, projw_b);

  gemm128_db<<<dim3(S_TOT / 128, TDIM / 128), 256, 0, stream>>>(
      hs_b, qkvw_b, qkv_b, qkv_b16, S_TOT, TDIM, DIM);

  pack_all<<<QK_BLOCKS + V_BLOCKS, 256, 0, stream>>>(qkv_b16, cosp, sinp, Qp, Kp, Vp);

  attn_mfma<<<dim3(16, NH * 2, 3), 256, 0, stream>>>(Qp, Kp, Vp, O0, O1, l0, l1);
  attn_combine<<<(S_TOT * DIM / 4) / 256, 256, 0, stream>>>(O0, O1, l0, l1, attn_b);

  gemm2_db<<<dim3(S_TOT / 64, DIM / 128), 256, 0, stream>>>(
      attn_b, projw_b, proj_b, out_f, S_TOT, DIM, DIM);
}

// Round 13
// 209.729 us; speedup vs baseline: 1.3686x; 1.2499x over previous
//
#include <hip/hip_runtime.h>
#include <hip/hip_bf16.h>

// Round 13: coalesced GEMM staging. Diagnosis: staging loads were K-strided
// (64 cache lines per wave-load -> TA request-rate bound at ~77 us, immune to
// pipelining/barriers/L2 locality, r5-r12). New staging: lane octet reads one
// row's 128 B run (8 lines/wave-load, 8x fewer requests), ds_write into
// [kh][row][8] planes (+16 B pad/plane), BK=64, reg-prefetch 1-barrier loop.
// Attention: r10 fused version restored (r12 split-K lost 7 us net).
//
// ws layout (r10):
//   [A] qkv_b16: 3072*3840 bf16 (23.6 MB)
//   [B] hs_b   : 3072*1280 bf16 (7.9 MB)  -- reused as attn_b after gemm1
//   [C] qkvw_b : 3840*1280 bf16 (9.8 MB)  -- Qp aliases after gemm1
//   [D] projw_b: 1280*1280 bf16 (3.3 MB)
//   [E] Kp     : 9.4 MB   [F] Vp: 9.4 MB (96-wide, col80 = ones)

#define S_TOT 3072
#define DIM   1280
#define NH    16
#define HD    80
#define SEG   1024
#define TDIM  3840

typedef short v8s __attribute__((ext_vector_type(8)));
typedef float v4f __attribute__((ext_vector_type(4)));

#define PS128 1032  // plane stride (shorts) for 128-row tile: 128*8 + 8 pad
#define PS64  520   // plane stride for 64-row tile: 64*8 + 8 pad

__device__ __forceinline__ short f2bf(float v) {
  __hip_bfloat16 b = __float2bfloat16(v);
  return *reinterpret_cast<short*>(&b);
}

__device__ __forceinline__ float bf2f(short s) {
  unsigned u = ((unsigned)(unsigned short)s) << 16;
  float f;
  __builtin_memcpy(&f, &u, 4);
  return f;
}

#define CVT_N1 (S_TOT * DIM / 4)
#define CVT_N2 (TDIM * DIM / 4)
#define CVT_N3 (DIM * DIM / 4)
__global__ __launch_bounds__(256) void cvt3(const float* __restrict__ in1,
                                            const float* __restrict__ in2,
                                            const float* __restrict__ in3,
                                            __hip_bfloat16* __restrict__ o1,
                                            __hip_bfloat16* __restrict__ o2,
                                            __hip_bfloat16* __restrict__ o3) {
  int i = blockIdx.x * 256 + threadIdx.x;
  const float* in;
  __hip_bfloat16* out;
  if (i < CVT_N1) { in = in1; out = o1; }
  else if (i < CVT_N1 + CVT_N2) { in = in2; out = o2; i -= CVT_N1; }
  else { in = in3; out = o3; i -= CVT_N1 + CVT_N2; }
  const float4 v = ((const float4*)in)[i];
  __hip_bfloat162 p0, p1;
  p0.x = __float2bfloat16(v.x); p0.y = __float2bfloat16(v.y);
  p1.x = __float2bfloat16(v.z); p1.y = __float2bfloat16(v.w);
  __hip_bfloat162* o = (__hip_bfloat162*)(out + (size_t)i * 4);
  o[0] = p0; o[1] = p1;
}

// ---------------- gemm1: 128x128, BK=64, coalesced staging ----------------
// Staging: chunk id = l*256+tid; row = id>>3, kh = id&7 -> lane octet reads
// 128 B of one row (8 lines/wave-load). LDS image: plane kh (stride PS128),
// chunk at kh*PS128 + row*8 shorts. Frag reads identical pattern to r10.
__global__ __launch_bounds__(256) void gemm1_c(const __hip_bfloat16* __restrict__ A,
                                               const __hip_bfloat16* __restrict__ B,
                                               const float* __restrict__ bias,
                                               __hip_bfloat16* __restrict__ C,
                                               int M, int N, int K) {
  __shared__ __align__(16) short Abuf[2][8 * PS128];  // 16.1 KB each
  __shared__ __align__(16) short Bbuf[2][8 * PS128];
  const int tid  = threadIdx.x;
  const int wave = tid >> 6;
  const int lane = tid & 63;
  const int quad = lane >> 4;
  const int l16  = lane & 15;
  const int bm = blockIdx.x * 128;   // M fastest: consecutive blocks share B
  const int bn = blockIdx.y * 128;
  const int wm = (wave >> 1) * 64;
  const int wn = (wave & 1) * 64;

  // staging bases: load l covers rows l*32 + (tid>>3), k-chunk kh = tid&7
  const int srow = tid >> 3;
  const int skh  = tid & 7;
  const __hip_bfloat16* Ag[4];
  const __hip_bfloat16* Bg[4];
  int Ao[4], Bo[4];
  #pragma unroll
  for (int l = 0; l < 4; ++l) {
    const int row = l * 32 + srow;
    Ag[l] = A + (size_t)(bm + row) * K + skh * 8;
    Bg[l] = B + (size_t)(bn + row) * K + skh * 8;
    Ao[l] = skh * PS128 + row * 8;
    Bo[l] = skh * PS128 + row * 8;
  }

  v4f acc[4][4];
  const v4f vz = {0.f, 0.f, 0.f, 0.f};
  #pragma unroll
  for (int i = 0; i < 4; ++i)
    #pragma unroll
    for (int j = 0; j < 4; ++j) acc[i][j] = vz;

  const int nk = K >> 6;  // 20 slabs of 64
  v8s ra[4], rb[4];

  #pragma unroll
  for (int l = 0; l < 4; ++l) { ra[l] = *(const v8s*)Ag[l]; rb[l] = *(const v8s*)Bg[l]; }
  #pragma unroll
  for (int l = 0; l < 4; ++l) {
    *(v8s*)&Abuf[0][Ao[l]] = ra[l];
    *(v8s*)&Bbuf[0][Bo[l]] = rb[l];
  }
  __syncthreads();

  for (int k = 0; k < nk; ++k) {
    const int cur = k & 1;
    const bool more = (k + 1 < nk);
    if (more) {
      const int off = (k + 1) * 64;
      #pragma unroll
      for (int l = 0; l < 4; ++l) {
        ra[l] = *(const v8s*)(Ag[l] + off);
        rb[l] = *(const v8s*)(Bg[l] + off);
      }
    }
    #pragma unroll
    for (int s = 0; s < 2; ++s) {
      v8s af[4], bf[4];
      #pragma unroll
      for (int i = 0; i < 4; ++i) {
        af[i] = *(const v8s*)&Abuf[cur][(s * 4 + quad) * PS128 + (wm + i * 16 + l16) * 8];
        bf[i] = *(const v8s*)&Bbuf[cur][(s * 4 + quad) * PS128 + (wn + i * 16 + l16) * 8];
      }
      #pragma unroll
      for (int i = 0; i < 4; ++i)
        #pragma unroll
        for (int j = 0; j < 4; ++j)
          acc[i][j] = __builtin_amdgcn_mfma_f32_16x16x32_bf16(af[i], bf[j], acc[i][j], 0, 0, 0);
    }
    if (more) {
      #pragma unroll
      for (int l = 0; l < 4; ++l) {
        *(v8s*)&Abuf[1 - cur][Ao[l]] = ra[l];
        *(v8s*)&Bbuf[1 - cur][Bo[l]] = rb[l];
      }
    }
    __syncthreads();
  }

  #pragma unroll
  for (int j = 0; j < 4; ++j) {
    const int col = bn + wn + j * 16 + l16;
    const float bj = bias[col];
    #pragma unroll
    for (int i = 0; i < 4; ++i) {
      const int row0 = bm + wm + i * 16 + quad * 4;
      #pragma unroll
      for (int r = 0; r < 4; ++r)
        C[(size_t)(row0 + r) * N + col] = __float2bfloat16(acc[i][j][r] + bj);
    }
  }
}

// ---------------- gemm2: 64x128, BK=64, coalesced staging, fp32 out ----------
__global__ __launch_bounds__(256) void gemm2_c(const __hip_bfloat16* __restrict__ A,
                                               const __hip_bfloat16* __restrict__ B,
                                               const float* __restrict__ bias,
                                               float* __restrict__ C,
                                               int M, int N, int K) {
  __shared__ __align__(16) short Abuf[2][8 * PS64];   // 8.1 KB each
  __shared__ __align__(16) short Bbuf[2][8 * PS128];  // 16.1 KB each
  const int tid  = threadIdx.x;
  const int wave = tid >> 6;
  const int lane = tid & 63;
  const int quad = lane >> 4;
  const int l16  = lane & 15;
  const int bm = blockIdx.x * 64;    // M fastest
  const int bn = blockIdx.y * 128;
  const int wm = (wave & 1) * 32;
  const int wn = (wave >> 1) * 64;

  const int srow = tid >> 3;
  const int skh  = tid & 7;
  const __hip_bfloat16* Ag[2];
  const __hip_bfloat16* Bg[4];
  int Ao[2], Bo[4];
  #pragma unroll
  for (int l = 0; l < 2; ++l) {
    const int row = l * 32 + srow;
    Ag[l] = A + (size_t)(bm + row) * K + skh * 8;
    Ao[l] = skh * PS64 + row * 8;
  }
  #pragma unroll
  for (int l = 0; l < 4; ++l) {
    const int row = l * 32 + srow;
    Bg[l] = B + (size_t)(bn + row) * K + skh * 8;
    Bo[l] = skh * PS128 + row * 8;
  }

  v4f acc[2][4];
  const v4f vz = {0.f, 0.f, 0.f, 0.f};
  #pragma unroll
  for (int i = 0; i < 2; ++i)
    #pragma unroll
    for (int j = 0; j < 4; ++j) acc[i][j] = vz;

  const int nk = K >> 6;
  v8s ra[2], rb[4];

  #pragma unroll
  for (int l = 0; l < 2; ++l) ra[l] = *(const v8s*)Ag[l];
  #pragma unroll
  for (int l = 0; l < 4; ++l) rb[l] = *(const v8s*)Bg[l];
  #pragma unroll
  for (int l = 0; l < 2; ++l) *(v8s*)&Abuf[0][Ao[l]] = ra[l];
  #pragma unroll
  for (int l = 0; l < 4; ++l) *(v8s*)&Bbuf[0][Bo[l]] = rb[l];
  __syncthreads();

  for (int k = 0; k < nk; ++k) {
    const int cur = k & 1;
    const bool more = (k + 1 < nk);
    if (more) {
      const int off = (k + 1) * 64;
      #pragma unroll
      for (int l = 0; l < 2; ++l) ra[l] = *(const v8s*)(Ag[l] + off);
      #pragma unroll
      for (int l = 0; l < 4; ++l) rb[l] = *(const v8s*)(Bg[l] + off);
    }
    #pragma unroll
    for (int s = 0; s < 2; ++s) {
      v8s af[2], bf[4];
      #pragma unroll
      for (int i = 0; i < 2; ++i)
        af[i] = *(const v8s*)&Abuf[cur][(s * 4 + quad) * PS64 + (wm + i * 16 + l16) * 8];
      #pragma unroll
      for (int j = 0; j < 4; ++j)
        bf[j] = *(const v8s*)&Bbuf[cur][(s * 4 + quad) * PS128 + (wn + j * 16 + l16) * 8];
      #pragma unroll
      for (int i = 0; i < 2; ++i)
        #pragma unroll
        for (int j = 0; j < 4; ++j)
          acc[i][j] = __builtin_amdgcn_mfma_f32_16x16x32_bf16(af[i], bf[j], acc[i][j], 0, 0, 0);
    }
    if (more) {
      #pragma unroll
      for (int l = 0; l < 2; ++l) *(v8s*)&Abuf[1 - cur][Ao[l]] = ra[l];
      #pragma unroll
      for (int l = 0; l < 4; ++l) *(v8s*)&Bbuf[1 - cur][Bo[l]] = rb[l];
    }
    __syncthreads();
  }

  #pragma unroll
  for (int j = 0; j < 4; ++j) {
    const int col = bn + wn + j * 16 + l16;
    const float bj = bias[col];
    #pragma unroll
    for (int i = 0; i < 2; ++i) {
      const int row0 = bm + wm + i * 16 + quad * 4;
      #pragma unroll
      for (int r = 0; r < 4; ++r)
        C[(size_t)(row0 + r) * N + col] = acc[i][j][r] + bj;
    }
  }
}

// ---------------- merged pack kernel (unchanged) ----------------
#define QK_BLOCKS ((2 * S_TOT * 16 * 12) / 256)   // 4608
#define V_BLOCKS  ((3 * 16 * 16 * 8 * 96) / 256)  // 2304
__global__ __launch_bounds__(256) void pack_all(const __hip_bfloat16* __restrict__ qkv,
                                                const float* __restrict__ cos_,
                                                const float* __restrict__ sin_,
                                                short* __restrict__ Qp,
                                                short* __restrict__ Kp,
                                                short* __restrict__ Vp) {
  const int bid = blockIdx.x;
  if (bid < QK_BLOCKS) {
    const int idx = bid * 256 + threadIdx.x;
    const int kd = idx % 12;
    const int h  = (idx / 12) % 16;
    const int s  = (idx / 192) % S_TOT;
    const int p  = idx / (192 * S_TOT);
    const int seg = s >> 10, tb = (s >> 6) & 15, t = s & 63;
    short* out = (p ? Kp : Qp) +
                 ((size_t)(((seg * 16 + h) * 16 + tb) * 12 + kd) * 64 + t) * 8;
    short tmp[8];
    if (kd >= 10) {
      #pragma unroll
      for (int j = 0; j < 8; ++j) tmp[j] = 0;
      *(int4*)out = *(int4*)tmp;
      return;
    }
    const short* row = (const short*)qkv + (size_t)s * TDIM + p * DIM + h * HD;
    const int d0 = kd * 8;
    const v8s xm = *(const v8s*)(row + d0);
    const v8s xr = *(const v8s*)(row + d0 + ((kd < 5) ? 40 : -40));
    const float sgn = (kd < 5) ? -1.f : 1.f;
    const float scale = (p == 0) ? 0.111803398874989485f : 1.0f;
    #pragma unroll
    for (int j = 0; j < 8; ++j) {
      const int d = d0 + j;
      const float v = (bf2f(xm[j]) * cos_[s * HD + d] +
                       sgn * bf2f(xr[j]) * sin_[s * HD + d]) * scale;
      tmp[j] = f2bf(v);
    }
    *(int4*)out = *(int4*)tmp;
  } else {
    const int idx = (bid - QK_BLOCKS) * 256 + threadIdx.x;
    const int d  = idx % 96;
    const int td = (idx / 96) % 8;
    const int tb = (idx / 768) % 16;
    const int h  = (idx / (768 * 16)) % 16;
    const int seg = idx / (768 * 256);
    const int s0 = seg * SEG + tb * 64 + td * 8;
    const short* q = (const short*)qkv;
    short tmp[8];
    if (d < 80) {
      #pragma unroll
      for (int j = 0; j < 8; ++j)
        tmp[j] = q[(size_t)(s0 + j) * TDIM + 2 * DIM + h * HD + d];
    } else {
      const short fill = (d == 80) ? (short)0x3F80 : (short)0;
      #pragma unroll
      for (int j = 0; j < 8; ++j) tmp[j] = fill;
    }
    *(int4*)(Vp + (size_t)idx * 8) = *(int4*)tmp;
  }
}

// ---------------- fused flash MFMA attention (r10 version) ----------------
__global__ __launch_bounds__(256, 3) void attn_mfma(const short* __restrict__ Qp,
                                                    const short* __restrict__ Kp,
                                                    const short* __restrict__ Vp,
                                                    __hip_bfloat16* __restrict__ out) {
  __shared__ __align__(16) short Qs[64 * 96];
  __shared__ __align__(16) short Ks[64 * 96];
  __shared__ __align__(16) short Vs[64 * 96];
  __shared__ __align__(16) short Ps[4][16 * 68];

  const int qt  = blockIdx.x;
  const int h   = blockIdx.y;
  const int seg = blockIdx.z;
  const int tid  = threadIdx.x;
  const int wave = tid >> 6;
  const int lane = tid & 63;
  const int quad = lane >> 4;
  const int l16  = lane & 15;
  const int sh16 = seg * 16 + h;

  const short* Qg = Qp + (size_t)(sh16 * 16 + qt) * 6144;
  const short* Kg = Kp + (size_t)sh16 * 16 * 6144;
  const short* Vg = Vp + (size_t)sh16 * 16 * 6144;

  v8s qr[3], kr[3], vr[3];
  #pragma unroll
  for (int it = 0; it < 3; ++it) {
    const int o = (it * 256 + tid) * 8;
    qr[it] = *(const v8s*)(Qg + o);
    kr[it] = *(const v8s*)(Kg + o);
    vr[it] = *(const v8s*)(Vg + o);
  }
  #pragma unroll
  for (int it = 0; it < 3; ++it) {
    const int o = (it * 256 + tid) * 8;
    *(v8s*)&Qs[o] = qr[it];
    *(v8s*)&Ks[o] = kr[it];
    *(v8s*)&Vs[o] = vr[it];
  }
  __syncthreads();

  v8s af[3];
  #pragma unroll
  for (int ks = 0; ks < 3; ++ks)
    af[ks] = *(const v8s*)&Qs[((ks * 4 + quad) * 64 + wave * 16 + l16) * 8];

  v4f o4[6];
  const v4f vz = {0.f, 0.f, 0.f, 0.f};
  #pragma unroll
  for (int n = 0; n < 6; ++n) o4[n] = vz;

  for (int kb = 0; kb < 16; ++kb) {
    const bool more = (kb + 1 < 16);
    if (more) {
      const size_t base = (size_t)(kb + 1) * 6144;
      #pragma unroll
      for (int it = 0; it < 3; ++it) {
        const int o = (it * 256 + tid) * 8;
        kr[it] = *(const v8s*)(Kg + base + o);
        vr[it] = *(const v8s*)(Vg + base + o);
      }
    }

    v4f s4[4];
    #pragma unroll
    for (int j = 0; j < 4; ++j) {
      s4[j] = vz;
      #pragma unroll
      for (int ks = 0; ks < 3; ++ks) {
        const v8s bf = *(const v8s*)&Ks[((ks * 4 + quad) * 64 + j * 16 + l16) * 8];
        s4[j] = __builtin_amdgcn_mfma_f32_16x16x32_bf16(af[ks], bf, s4[j], 0, 0, 0);
      }
    }

    #pragma unroll
    for (int reg = 0; reg < 4; ++reg)
      #pragma unroll
      for (int j = 0; j < 4; ++j)
        Ps[wave][(quad * 4 + reg) * 68 + j * 16 + l16] = f2bf(__expf(s4[j][reg]));

    v8s pa[2];
    #pragma unroll
    for (int kp = 0; kp < 2; ++kp)
      pa[kp] = *(const v8s*)&Ps[wave][l16 * 68 + kp * 32 + quad * 8];
    #pragma unroll
    for (int n = 0; n < 6; ++n) {
      #pragma unroll
      for (int kp = 0; kp < 2; ++kp) {
        const v8s vb = *(const v8s*)&Vs[((kp * 4 + quad) * 96 + n * 16 + l16) * 8];
        o4[n] = __builtin_amdgcn_mfma_f32_16x16x32_bf16(pa[kp], vb, o4[n], 0, 0, 0);
      }
    }

    __syncthreads();
    if (more) {
      #pragma unroll
      for (int it = 0; it < 3; ++it) {
        const int o = (it * 256 + tid) * 8;
        *(v8s*)&Ks[o] = kr[it];
        *(v8s*)&Vs[o] = vr[it];
      }
    }
    __syncthreads();
  }

  float inv[4];
  #pragma unroll
  for (int r = 0; r < 4; ++r)
    inv[r] = 1.f / __shfl(o4[5][r], quad << 4);
  const int row0 = seg * SEG + qt * 64 + wave * 16 + quad * 4;
  #pragma unroll
  for (int n = 0; n < 5; ++n) {
    const int col = h * HD + n * 16 + l16;
    #pragma unroll
    for (int r = 0; r < 4; ++r)
      out[(size_t)(row0 + r) * DIM + col] = __float2bfloat16(o4[n][r] * inv[r]);
  }
}

extern "C" void kernel_launch(void* const* d_in, const int* in_sizes, int n_in,
                              void* d_out, int out_size, void* d_ws, size_t ws_size,
                              hipStream_t stream) {
  (void)in_sizes; (void)n_in; (void)out_size; (void)ws_size;
  const float* hs     = (const float*)d_in[0];
  const float* cosp   = (const float*)d_in[1];
  const float* sinp   = (const float*)d_in[2];
  const float* qkv_w  = (const float*)d_in[3];
  const float* qkv_b  = (const float*)d_in[4];
  const float* proj_w = (const float*)d_in[5];
  const float* proj_b = (const float*)d_in[6];

  float* out_f = (float*)d_out;
  __hip_bfloat16* qkv_b16 = (__hip_bfloat16*)d_ws;                     // [A]
  __hip_bfloat16* hs_b    = qkv_b16 + (size_t)S_TOT * TDIM;            // [B]
  __hip_bfloat16* qkvw_b  = hs_b + (size_t)S_TOT * DIM;                // [C]
  __hip_bfloat16* projw_b = qkvw_b + (size_t)TDIM * DIM;               // [D]
  short* Qp = (short*)qkvw_b;                                          // alias [C]
  short* Kp = (short*)(projw_b + (size_t)DIM * DIM);                   // [E]
  short* Vp = Kp + (size_t)3 * 16 * 16 * 6144;                         // [F]
  __hip_bfloat16* attn_b = hs_b;                                       // alias [B]

  cvt3<<<(CVT_N1 + CVT_N2 + CVT_N3) / 256, 256, 0, stream>>>(
      hs, qkv_w, proj_w, hs_b, qkvw_b, projw_b);

  gemm1_c<<<dim3(S_TOT / 128, TDIM / 128), 256, 0, stream>>>(
      hs_b, qkvw_b, qkv_b, qkv_b16, S_TOT, TDIM, DIM);

  pack_all<<<QK_BLOCKS + V_BLOCKS, 256, 0, stream>>>(qkv_b16, cosp, sinp, Qp, Kp, Vp);

  attn_mfma<<<dim3(16, NH, 3), 256, 0, stream>>>(Qp, Kp, Vp, attn_b);

  gemm2_c<<<dim3(S_TOT / 64, DIM / 128), 256, 0, stream>>>(
      attn_b, projw_b, proj_b, out_f, S_TOT, DIM, DIM);
}